// Round 9
// baseline (373.625 us; speedup 1.0000x reference)
//
#include <hip/hip_runtime.h>
#include <math.h>

#define FIN 128   // input features (layer1 K, layer2 K)
#define F1  128   // H1*C1 = layer1 output width
#define C2  64    // layer2 output width
#define NEG 0.2f  // leaky_relu negative slope

#define BKT_SHIFT 8
#define BKT_SIZE  256     // nodes per bucket
#define SCAT_CHUNK 8192   // edges per block in hist/scatter
#define IMGCAP 8192       // LDS csr-image capacity (ints)

typedef _Float16 half4 __attribute__((ext_vector_type(4)));
typedef _Float16 f16x8 __attribute__((ext_vector_type(8)));
typedef _Float16 h2    __attribute__((ext_vector_type(2)));
typedef float    f32x4 __attribute__((ext_vector_type(4)));

union H8u { f16x8 v; h2 p[4]; };

// ================= prep: bucket histogram + weight transpose (independent work) =================
// blocks [0, sblocks): histogram; blocks [sblocks, sblocks+192): wtrans over 49152 elems.
__global__ __launch_bounds__(256) void prep_kernel(
    const int* __restrict__ ei, int* __restrict__ bcnt, int E, int ET, int NBKT, int sblocks,
    const float* __restrict__ W0, const float* __restrict__ W1,
    const float* __restrict__ W2, const float* __restrict__ W3,
    _Float16* __restrict__ T0, _Float16* __restrict__ T1,
    _Float16* __restrict__ T2, _Float16* __restrict__ T3) {
  const int t = threadIdx.x;
  if ((int)blockIdx.x < sblocks) {
    __shared__ int sh[512];
    for (int b = t; b < NBKT; b += 256) sh[b] = 0;
    __syncthreads();
    const int g0 = blockIdx.x * SCAT_CHUNK + t;
#pragma unroll
    for (int i = 0; i < 32; ++i) {
      const int g = g0 + i * 256;
      if (g < ET) {
        const int dst = (g < E) ? ei[E + g] : (g - E);
        atomicAdd(&sh[dst >> BKT_SHIFT], 1);
      }
    }
    __syncthreads();
    for (int b = t; b < NBKT; b += 256)
      if (sh[b]) atomicAdd(&bcnt[b], sh[b]);
  } else {
    const int idx = ((int)blockIdx.x - sblocks) * 256 + t;   // [0, 49152)
    // ranges: [0,16384) T0; [16384,32768) T1; [32768,40960) T2; [40960,49152) T3
    const float* W; _Float16* T; int local, ncols;
    if (idx < 16384)      { W = W0; T = T0; local = idx;        ncols = 128; }
    else if (idx < 32768) { W = W1; T = T1; local = idx-16384;  ncols = 128; }
    else if (idx < 40960) { W = W2; T = T2; local = idx-32768;  ncols = 64;  }
    else                  { W = W3; T = T3; local = idx-40960;  ncols = 64;  }
    const int n = local >> 7;
    const int k = local & 127;
    T[local] = (_Float16)W[k * ncols + n];
  }
}

__global__ __launch_bounds__(512) void bucket_scan_kernel(
    const int* __restrict__ bcnt, int* __restrict__ bbase, int* __restrict__ bcur,
    int* __restrict__ indptr, int NBKT, int N, int ET) {
  __shared__ int sh[512];
  const int t = threadIdx.x;
  const int v = (t < NBKT) ? bcnt[t] : 0;
  sh[t] = v;
  __syncthreads();
  for (int off = 1; off < 512; off <<= 1) {
    int val = (t >= off) ? sh[t - off] : 0;
    __syncthreads();
    sh[t] += val;
    __syncthreads();
  }
  const int excl = sh[t] - v;
  if (t < NBKT) { bbase[t] = excl; bcur[t] = excl; }
  if (t == NBKT - 1) bbase[NBKT] = excl + v;   // == ET
  if (t == 0) indptr[N] = ET;
}

__global__ __launch_bounds__(256) void bucket_scatter_kernel(
    const int* __restrict__ ei, int* __restrict__ bcur, int* __restrict__ tmp,
    int E, int ET, int NBKT) {
  __shared__ int sh_hist[512];
  __shared__ int sh_base[512];
  const int t = threadIdx.x;
  for (int b = t; b < NBKT; b += 256) sh_hist[b] = 0;
  __syncthreads();
  const int g0 = blockIdx.x * SCAT_CHUNK + t;
  int bk[32], pk[32];
#pragma unroll
  for (int i = 0; i < 32; ++i) {
    const int g = g0 + i * 256;
    int b = -1, p = 0;
    if (g < ET) {
      const int src = (g < E) ? ei[g] : (g - E);
      const int dst = (g < E) ? ei[E + g] : (g - E);
      b = dst >> BKT_SHIFT;
      p = (src << BKT_SHIFT) | (dst & (BKT_SIZE - 1));
      atomicAdd(&sh_hist[b], 1);
    }
    bk[i] = b; pk[i] = p;
  }
  __syncthreads();
  for (int b = t; b < NBKT; b += 256) {
    const int c = sh_hist[b];
    sh_base[b] = c ? atomicAdd(&bcur[b], c) : 0;
    sh_hist[b] = 0;   // reuse as in-block cursor
  }
  __syncthreads();
#pragma unroll
  for (int i = 0; i < 32; ++i) {
    if (bk[i] >= 0) {
      const int off = atomicAdd(&sh_hist[bk[i]], 1);
      tmp[sh_base[bk[i]] + off] = pk[i];
    }
  }
}

__global__ __launch_bounds__(256) void build_csr_kernel(
    const int* __restrict__ tmp, const int* __restrict__ bbase,
    int* __restrict__ indptr, int* __restrict__ csr, int N) {
  __shared__ int cnt[256];
  __shared__ int cur[256];
  __shared__ int img[IMGCAP];
  const int b = blockIdx.x;
  const int t = threadIdx.x;
  const int base = bbase[b];
  const int cntb = bbase[b + 1] - base;
  cnt[t] = 0;
  __syncthreads();
  for (int i = t; i < cntb; i += 256)
    atomicAdd(&cnt[tmp[base + i] & (BKT_SIZE - 1)], 1);
  __syncthreads();
  const int v = cnt[t];
  cur[t] = v;
  __syncthreads();
  for (int off = 1; off < 256; off <<= 1) {
    int val = (t >= off) ? cur[t - off] : 0;
    __syncthreads();
    cur[t] += val;
    __syncthreads();
  }
  const int excl = cur[t] - v;
  const int node = (b << BKT_SHIFT) + t;
  if (node < N) indptr[node] = base + excl;
  __syncthreads();
  cur[t] = excl;
  __syncthreads();
  if (cntb <= IMGCAP) {
    for (int i = t; i < cntb; i += 256) {
      const int p = tmp[base + i];
      const int pos = atomicAdd(&cur[p & (BKT_SIZE - 1)], 1);
      img[pos] = p >> BKT_SHIFT;
    }
    __syncthreads();
    for (int i = t; i < cntb; i += 256) csr[base + i] = img[i];
  } else {
    for (int i = t; i < cntb; i += 256) {
      const int p = tmp[base + i];
      const int pos = atomicAdd(&cur[p & (BKT_SIZE - 1)], 1);
      csr[base + pos] = p >> BKT_SHIFT;
    }
  }
}

// ---------------- fp16 MFMA GEMM: O = A[M,128] @ W[128,NCOLS] + b, fp16 out ----------------
// LDS-free. Block = 4 waves; wave covers CPW col-tiles. AF32: A is fp32, cvt in-register.
template<int NCOLS, int CPW, bool AF32>
__global__ __launch_bounds__(256) void gemm_mfma_kernel(
    const void* __restrict__ Av,
    const _Float16* __restrict__ Wt0, const float* __restrict__ b0, _Float16* __restrict__ O0,
    const _Float16* __restrict__ Wt1, const float* __restrict__ b1, _Float16* __restrict__ O1,
    int M) {
  const _Float16* A16 = (const _Float16*)Av;
  const float*    A32 = (const float*)Av;
  const int zsel = blockIdx.z;
  const _Float16* Wt = zsel ? Wt1 : Wt0;
  const float* bias  = zsel ? b1 : b0;
  _Float16* O        = zsel ? O1 : O0;
  const int wave = threadIdx.x >> 6;
  const int lane = threadIdx.x & 63;
  const int row16 = lane & 15;
  const int quad  = lane >> 4;
  const int kb = quad * 8;
  f16x8 bfrag[CPW][4];
  float bv[CPW];
#pragma unroll
  for (int c = 0; c < CPW; ++c) {
    const int n0 = (wave * CPW + c) * 16;
    bv[c] = bias[n0 + row16];
#pragma unroll
    for (int kt = 0; kt < 4; ++kt)
      bfrag[c][kt] = *(const f16x8*)(Wt + (n0 + row16) * 128 + kt * 32 + kb);
  }
  const int rowTiles = (M + 15) >> 4;
  for (int rt = blockIdx.x; rt < rowTiles; rt += gridDim.x) {
    const int r0 = rt << 4;
    const int arow = min(r0 + row16, M - 1);
    f16x8 afrag[4];
    if (AF32) {
#pragma unroll
      for (int kt = 0; kt < 4; ++kt) {
        const float4 u = *(const float4*)(A32 + (size_t)arow * 128 + kt * 32 + kb);
        const float4 w = *(const float4*)(A32 + (size_t)arow * 128 + kt * 32 + kb + 4);
        f16x8 f;
        f[0] = (_Float16)u.x; f[1] = (_Float16)u.y; f[2] = (_Float16)u.z; f[3] = (_Float16)u.w;
        f[4] = (_Float16)w.x; f[5] = (_Float16)w.y; f[6] = (_Float16)w.z; f[7] = (_Float16)w.w;
        afrag[kt] = f;
      }
    } else {
#pragma unroll
      for (int kt = 0; kt < 4; ++kt)
        afrag[kt] = *(const f16x8*)(A16 + (size_t)arow * 128 + kt * 32 + kb);
    }
    f32x4 acc[CPW];
#pragma unroll
    for (int c = 0; c < CPW; ++c) acc[c] = (f32x4){0.f, 0.f, 0.f, 0.f};
#pragma unroll
    for (int kt = 0; kt < 4; ++kt)
#pragma unroll
      for (int c = 0; c < CPW; ++c)
        acc[c] = __builtin_amdgcn_mfma_f32_16x16x32_f16(afrag[kt], bfrag[c][kt], acc[c], 0, 0, 0);
#pragma unroll
    for (int c = 0; c < CPW; ++c) {
      const int col = (wave * CPW + c) * 16 + row16;
#pragma unroll
      for (int r = 0; r < 4; ++r) {
        const int row = r0 + quad * 4 + r;
        if (row < M)
          O[(size_t)row * NCOLS + col] = (_Float16)(acc[c][r] + bv[c]);
      }
    }
  }
}

// ---------------- layer 1 fused attention: 16 lanes/node x 8 chans, 8-deep batches ----------------
__global__ __launch_bounds__(256) void attn1_kernel(
    const _Float16* __restrict__ xl, const _Float16* __restrict__ xr,
    const float* __restrict__ att, const float* __restrict__ bias,
    const int* __restrict__ indptr, const int* __restrict__ csr,
    _Float16* __restrict__ hout, int N) {
  const int lane = threadIdx.x & 15;
  const int v = blockIdx.x * 16 + (threadIdx.x >> 4);
  if (v >= N) return;
  const int c8 = lane << 3;
  const _Float16* xlp = xl + c8;
  H8u xru; xru.v = *(const f16x8*)(xr + (v << 7) + c8);
  H8u atu;
  {
    const float4 a0 = *(const float4*)(att + c8);
    const float4 a1 = *(const float4*)(att + c8 + 4);
    f16x8 a;
    a[0] = (_Float16)a0.x; a[1] = (_Float16)a0.y; a[2] = (_Float16)a0.z; a[3] = (_Float16)a0.w;
    a[4] = (_Float16)a1.x; a[5] = (_Float16)a1.y; a[6] = (_Float16)a1.z; a[7] = (_Float16)a1.w;
    atu.v = a;
  }
  const h2 neg2 = {(_Float16)NEG, (_Float16)NEG};
  const h2 zero2 = {(_Float16)0.f, (_Float16)0.f};
  const int beg = indptr[v];
  const int end = indptr[v + 1];
  float l = 0.f;
  float acc[8] = {0.f, 0.f, 0.f, 0.f, 0.f, 0.f, 0.f, 0.f};
  int e = beg;
  for (; e + 8 <= end; e += 8) {
    int s[8];
#pragma unroll
    for (int i = 0; i < 8; ++i) s[i] = csr[e + i];
    H8u xv[8];
#pragma unroll
    for (int i = 0; i < 8; ++i) xv[i].v = *(const f16x8*)(xlp + (s[i] << 7));
    float p[8];
#pragma unroll
    for (int i = 0; i < 8; ++i) {
      h2 sa = zero2;
#pragma unroll
      for (int j = 0; j < 4; ++j) {
        h2 ev = xv[i].p[j] + xru.p[j];
        ev = __builtin_elementwise_max(ev, ev * neg2);
        sa = ev * atu.p[j] + sa;
      }
      float tt = (float)(_Float16)(sa[0] + sa[1]);
      tt += __shfl_xor(tt, 1);
      p[i] = __expf(tt);
    }
#pragma unroll
    for (int i = 0; i < 8; ++i) {
      l += p[i];
#pragma unroll
      for (int j = 0; j < 4; ++j) {
        acc[2*j]   = fmaf(p[i], (float)xv[i].p[j][0], acc[2*j]);
        acc[2*j+1] = fmaf(p[i], (float)xv[i].p[j][1], acc[2*j+1]);
      }
    }
  }
  for (; e + 4 <= end; e += 4) {
    int s[4];
#pragma unroll
    for (int i = 0; i < 4; ++i) s[i] = csr[e + i];
    H8u xv[4];
#pragma unroll
    for (int i = 0; i < 4; ++i) xv[i].v = *(const f16x8*)(xlp + (s[i] << 7));
#pragma unroll
    for (int i = 0; i < 4; ++i) {
      h2 sa = zero2;
#pragma unroll
      for (int j = 0; j < 4; ++j) {
        h2 ev = xv[i].p[j] + xru.p[j];
        ev = __builtin_elementwise_max(ev, ev * neg2);
        sa = ev * atu.p[j] + sa;
      }
      float tt = (float)(_Float16)(sa[0] + sa[1]);
      tt += __shfl_xor(tt, 1);
      const float p = __expf(tt);
      l += p;
#pragma unroll
      for (int j = 0; j < 4; ++j) {
        acc[2*j]   = fmaf(p, (float)xv[i].p[j][0], acc[2*j]);
        acc[2*j+1] = fmaf(p, (float)xv[i].p[j][1], acc[2*j+1]);
      }
    }
  }
  for (; e < end; ++e) {
    const int s = csr[e];
    H8u xv; xv.v = *(const f16x8*)(xlp + (s << 7));
    h2 sa = zero2;
#pragma unroll
    for (int j = 0; j < 4; ++j) {
      h2 ev = xv.p[j] + xru.p[j];
      ev = __builtin_elementwise_max(ev, ev * neg2);
      sa = ev * atu.p[j] + sa;
    }
    float tt = (float)(_Float16)(sa[0] + sa[1]);
    tt += __shfl_xor(tt, 1);
    const float p = __expf(tt);
    l += p;
#pragma unroll
    for (int j = 0; j < 4; ++j) {
      acc[2*j]   = fmaf(p, (float)xv.p[j][0], acc[2*j]);
      acc[2*j+1] = fmaf(p, (float)xv.p[j][1], acc[2*j+1]);
    }
  }
  const float rl = 1.f / l;
  const float4 b0 = *(const float4*)(bias + c8);
  const float4 b1 = *(const float4*)(bias + c8 + 4);
  float r[8];
  r[0] = fmaf(acc[0], rl, b0.x); r[1] = fmaf(acc[1], rl, b0.y);
  r[2] = fmaf(acc[2], rl, b0.z); r[3] = fmaf(acc[3], rl, b0.w);
  r[4] = fmaf(acc[4], rl, b1.x); r[5] = fmaf(acc[5], rl, b1.y);
  r[6] = fmaf(acc[6], rl, b1.z); r[7] = fmaf(acc[7], rl, b1.w);
  f16x8 hres;
#pragma unroll
  for (int i = 0; i < 8; ++i) {
    const float z = r[i] > 0.f ? r[i] : expm1f(r[i]);   // ELU
    hres[i] = (_Float16)z;
  }
  *(f16x8*)(hout + (v << 7) + c8) = hres;
}

// ---------------- layer 2 fused attention: 8 lanes/node x 8 chans, 8-deep batches ----------------
__global__ __launch_bounds__(256) void attn2_kernel(
    const _Float16* __restrict__ xl, const _Float16* __restrict__ xr,
    const float* __restrict__ att, const float* __restrict__ bias,
    const int* __restrict__ indptr, const int* __restrict__ csr,
    float* __restrict__ out, int N) {
  const int lane = threadIdx.x & 7;
  const int v = blockIdx.x * 32 + (threadIdx.x >> 3);
  if (v >= N) return;
  const int c8 = lane << 3;
  const _Float16* xlp = xl + c8;
  H8u xru; xru.v = *(const f16x8*)(xr + (v << 6) + c8);
  H8u atu;
  {
    const float4 a0 = *(const float4*)(att + c8);
    const float4 a1 = *(const float4*)(att + c8 + 4);
    f16x8 a;
    a[0] = (_Float16)a0.x; a[1] = (_Float16)a0.y; a[2] = (_Float16)a0.z; a[3] = (_Float16)a0.w;
    a[4] = (_Float16)a1.x; a[5] = (_Float16)a1.y; a[6] = (_Float16)a1.z; a[7] = (_Float16)a1.w;
    atu.v = a;
  }
  const h2 neg2 = {(_Float16)NEG, (_Float16)NEG};
  const h2 zero2 = {(_Float16)0.f, (_Float16)0.f};
  const int beg = indptr[v];
  const int end = indptr[v + 1];
  float l = 0.f;
  float acc[8] = {0.f, 0.f, 0.f, 0.f, 0.f, 0.f, 0.f, 0.f};
  int e = beg;
  for (; e + 8 <= end; e += 8) {
    int s[8];
#pragma unroll
    for (int i = 0; i < 8; ++i) s[i] = csr[e + i];
    H8u xv[8];
#pragma unroll
    for (int i = 0; i < 8; ++i) xv[i].v = *(const f16x8*)(xlp + (s[i] << 6));
    float p[8];
#pragma unroll
    for (int i = 0; i < 8; ++i) {
      h2 sa = zero2;
#pragma unroll
      for (int j = 0; j < 4; ++j) {
        h2 ev = xv[i].p[j] + xru.p[j];
        ev = __builtin_elementwise_max(ev, ev * neg2);
        sa = ev * atu.p[j] + sa;
      }
      float tt = (float)(_Float16)(sa[0] + sa[1]);
      tt += __shfl_xor(tt, 1);
      tt += __shfl_xor(tt, 2);
      tt += __shfl_xor(tt, 4);
      p[i] = __expf(tt);
    }
#pragma unroll
    for (int i = 0; i < 8; ++i) {
      l += p[i];
#pragma unroll
      for (int j = 0; j < 4; ++j) {
        acc[2*j]   = fmaf(p[i], (float)xv[i].p[j][0], acc[2*j]);
        acc[2*j+1] = fmaf(p[i], (float)xv[i].p[j][1], acc[2*j+1]);
      }
    }
  }
  for (; e + 4 <= end; e += 4) {
    int s[4];
#pragma unroll
    for (int i = 0; i < 4; ++i) s[i] = csr[e + i];
    H8u xv[4];
#pragma unroll
    for (int i = 0; i < 4; ++i) xv[i].v = *(const f16x8*)(xlp + (s[i] << 6));
#pragma unroll
    for (int i = 0; i < 4; ++i) {
      h2 sa = zero2;
#pragma unroll
      for (int j = 0; j < 4; ++j) {
        h2 ev = xv[i].p[j] + xru.p[j];
        ev = __builtin_elementwise_max(ev, ev * neg2);
        sa = ev * atu.p[j] + sa;
      }
      float tt = (float)(_Float16)(sa[0] + sa[1]);
      tt += __shfl_xor(tt, 1);
      tt += __shfl_xor(tt, 2);
      tt += __shfl_xor(tt, 4);
      const float p = __expf(tt);
      l += p;
#pragma unroll
      for (int j = 0; j < 4; ++j) {
        acc[2*j]   = fmaf(p, (float)xv[i].p[j][0], acc[2*j]);
        acc[2*j+1] = fmaf(p, (float)xv[i].p[j][1], acc[2*j+1]);
      }
    }
  }
  for (; e < end; ++e) {
    const int s = csr[e];
    H8u xv; xv.v = *(const f16x8*)(xlp + (s << 6));
    h2 sa = zero2;
#pragma unroll
    for (int j = 0; j < 4; ++j) {
      h2 ev = xv.p[j] + xru.p[j];
      ev = __builtin_elementwise_max(ev, ev * neg2);
      sa = ev * atu.p[j] + sa;
    }
    float tt = (float)(_Float16)(sa[0] + sa[1]);
    tt += __shfl_xor(tt, 1);
    tt += __shfl_xor(tt, 2);
    tt += __shfl_xor(tt, 4);
    const float p = __expf(tt);
    l += p;
#pragma unroll
    for (int j = 0; j < 4; ++j) {
      acc[2*j]   = fmaf(p, (float)xv.p[j][0], acc[2*j]);
      acc[2*j+1] = fmaf(p, (float)xv.p[j][1], acc[2*j+1]);
    }
  }
  const float rl = 1.f / l;
  const float4 b0 = *(const float4*)(bias + c8);
  const float4 b1 = *(const float4*)(bias + c8 + 4);
  float4 o0, o1;
  o0.x = fmaf(acc[0], rl, b0.x); o0.y = fmaf(acc[1], rl, b0.y);
  o0.z = fmaf(acc[2], rl, b0.z); o0.w = fmaf(acc[3], rl, b0.w);
  o1.x = fmaf(acc[4], rl, b1.x); o1.y = fmaf(acc[5], rl, b1.y);
  o1.z = fmaf(acc[6], rl, b1.z); o1.w = fmaf(acc[7], rl, b1.w);
  *(float4*)(out + (v << 6) + c8) = o0;
  *(float4*)(out + (v << 6) + c8 + 4) = o1;
}

extern "C" void kernel_launch(void* const* d_in, const int* in_sizes, int n_in,
                              void* d_out, int out_size, void* d_ws, size_t ws_size,
                              hipStream_t stream) {
  const float* x     = (const float*)d_in[0];
  const int*   ei    = (const int*)d_in[1];
  const float* Wl1   = (const float*)d_in[2];
  const float* bl1   = (const float*)d_in[3];
  const float* Wr1   = (const float*)d_in[4];
  const float* br1   = (const float*)d_in[5];
  const float* att1  = (const float*)d_in[6];
  const float* bias1 = (const float*)d_in[7];
  const float* Wl2   = (const float*)d_in[8];
  const float* bl2   = (const float*)d_in[9];
  const float* Wr2   = (const float*)d_in[10];
  const float* br2   = (const float*)d_in[11];
  const float* att2  = (const float*)d_in[12];
  const float* bias2 = (const float*)d_in[13];

  const int N  = in_sizes[0] / FIN;   // 100000
  const int E  = in_sizes[1] / 2;     // 1600000
  const int ET = E + N;
  const int NBKT = (N + BKT_SIZE - 1) >> BKT_SHIFT;   // 391 (<=512 required)

  // workspace layout
  _Float16* xl1h  = (_Float16*)d_ws;                   // N*128 f16
  _Float16* xr1h  = xl1h + (size_t)N * F1;             // N*128 f16
  _Float16* hbufh = xr1h + (size_t)N * F1;             // N*128 f16
  _Float16* Wt1l  = hbufh + (size_t)N * F1;            // 128*128 f16
  _Float16* Wt1r  = Wt1l + 128 * 128;
  _Float16* Wt2l  = Wt1r + 128 * 128;                  // 64*128 f16
  _Float16* Wt2r  = Wt2l + 64 * 128;
  int* indptr = (int*)(Wt2r + 64 * 128);               // N+1
  int* csr    = indptr + (N + 1);                      // ET
  int* bcnt   = csr + ET;                              // 512
  int* bbase  = bcnt + 512;                            // 513
  int* bcur   = bbase + 513;                           // 512
  int* tmp    = (int*)hbufh;   // alias: dead before attn1 writes hbufh
  _Float16* xl2h = xl1h;                               // reuse after attn1
  _Float16* xr2h = xr1h;
  float* out  = (float*)d_out;

  const int sblocks = (ET + SCAT_CHUNK - 1) / SCAT_CHUNK;
  const int wblocks = 49152 / 256;   // 192

  hipMemsetAsync(bcnt, 0, 512 * sizeof(int), stream);
  prep_kernel<<<sblocks + wblocks, 256, 0, stream>>>(
      ei, bcnt, E, ET, NBKT, sblocks,
      Wl1, Wr1, Wl2, Wr2, Wt1l, Wt1r, Wt2l, Wt2r);
  bucket_scan_kernel<<<1, 512, 0, stream>>>(bcnt, bbase, bcur, indptr, NBKT, N, ET);
  bucket_scatter_kernel<<<sblocks, 256, 0, stream>>>(ei, bcur, tmp, E, ET, NBKT);
  build_csr_kernel<<<NBKT, 256, 0, stream>>>(tmp, bbase, indptr, csr, N);

  gemm_mfma_kernel<128, 2, true><<<dim3(1024, 1, 2), 256, 0, stream>>>(
      x, Wt1l, bl1, xl1h, Wt1r, br1, xr1h, N);

  attn1_kernel<<<(N + 15) / 16, 256, 0, stream>>>(xl1h, xr1h, att1, bias1, indptr, csr, hbufh, N);

  gemm_mfma_kernel<64, 1, false><<<dim3(1024, 1, 2), 256, 0, stream>>>(
      hbufh, Wt2l, bl2, xl2h, Wt2r, br2, xr2h, N);

  attn2_kernel<<<(N + 31) / 32, 256, 0, stream>>>(xl2h, xr2h, att2, bias2, indptr, csr, out, N);
}